// Round 1
// baseline (446.173 us; speedup 1.0000x reference)
//
#include <hip/hip_runtime.h>

#define HALO 10   // 11-tap window -> 10 halo
#define TW 32
#define TH 32

__device__ __forceinline__ void make_gauss(float* g) {
    float s = 0.f;
#pragma unroll
    for (int i = 0; i < 11; ++i) {
        float d = (float)(i - 5);
        g[i] = expf(-d * d / 4.5f);   // sigma=1.5 -> 2*sigma^2 = 4.5
        s += g[i];
    }
    float inv = 1.f / s;
#pragma unroll
    for (int i = 0; i < 11; ++i) g[i] *= inv;
}

// One (n,c) image pair, one 32x32 output tile per block.
// Separable 11x11 Gaussian conv of {x, y, x^2, y^2, x*y}, then SSIM/CS maps,
// block-reduced and atomically accumulated into acc[nc*2 + {0,1}].
__global__ __launch_bounds__(256) void ssim_scale_kernel(
    const float* __restrict__ x, const float* __restrict__ y,
    float* __restrict__ acc, int H, int W)
{
    const int OH = H - HALO, OW = W - HALO;
    const int nc = blockIdx.z;
    const size_t base = (size_t)nc * H * W;
    const float* xp = x + base;
    const float* yp = y + base;
    const int ty0 = blockIdx.y * TH;
    const int tx0 = blockIdx.x * TW;

    __shared__ float sx[TH + HALO][TW + HALO];   // 42x42
    __shared__ float sy[TH + HALO][TW + HALO];
    __shared__ float hx [TH + HALO][TW];         // 42x32 x5
    __shared__ float hy [TH + HALO][TW];
    __shared__ float hxx[TH + HALO][TW];
    __shared__ float hyy[TH + HALO][TW];
    __shared__ float hxy[TH + HALO][TW];
    __shared__ float red[8];

    float g[11];
    make_gauss(g);

    const int tid = threadIdx.x;

    // ---- load x/y tile (with halo), zero-fill OOB (only consumed by OOB outputs)
    for (int i = tid; i < (TH + HALO) * (TW + HALO); i += 256) {
        int r = i / (TW + HALO);
        int c = i - r * (TW + HALO);
        int gy = ty0 + r, gx = tx0 + c;
        float vx = 0.f, vy = 0.f;
        if (gy < H && gx < W) {
            vx = xp[(size_t)gy * W + gx];
            vy = yp[(size_t)gy * W + gx];
        }
        sx[r][c] = vx;
        sy[r][c] = vy;
    }
    __syncthreads();

    // ---- horizontal 11-tap pass over 5 fields (squares/products on the fly)
    for (int i = tid; i < (TH + HALO) * TW; i += 256) {
        int r = i >> 5;
        int c = i & 31;
        float ax = 0, ay = 0, axx = 0, ayy = 0, axy = 0;
#pragma unroll
        for (int j = 0; j < 11; ++j) {
            float a = sx[r][c + j];
            float b = sy[r][c + j];
            float w = g[j];
            ax  += w * a;
            ay  += w * b;
            axx += w * a * a;
            ayy += w * b * b;
            axy += w * a * b;
        }
        hx[r][c] = ax; hy[r][c] = ay;
        hxx[r][c] = axx; hyy[r][c] = ayy; hxy[r][c] = axy;
    }
    __syncthreads();

    // ---- vertical 11-tap pass + SSIM/CS + per-thread accumulation
    const float c1 = 0.0001f;  // (0.01*1)^2
    const float c2 = 0.0009f;  // (0.03*1)^2
    float ssim_acc = 0.f, cs_acc = 0.f;

    for (int i = tid; i < TH * TW; i += 256) {
        int r = i >> 5, c = i & 31;
        int oy = ty0 + r, ox = tx0 + c;
        if (oy < OH && ox < OW) {
            float mx = 0, my = 0, mxx = 0, myy = 0, mxy = 0;
#pragma unroll
            for (int j = 0; j < 11; ++j) {
                float w = g[j];
                mx  += w * hx [r + j][c];
                my  += w * hy [r + j][c];
                mxx += w * hxx[r + j][c];
                myy += w * hyy[r + j][c];
                mxy += w * hxy[r + j][c];
            }
            float mu_x2 = mx * mx, mu_y2 = my * my, mu_xy = mx * my;
            float sxq  = mxx - mu_x2;
            float syq  = myy - mu_y2;
            float sxyv = mxy - mu_xy;
            float cs   = (2.f * sxyv + c2) / (sxq + syq + c2);
            float ssim = (2.f * mu_xy + c1) / (mu_x2 + mu_y2 + c1) * cs;
            ssim_acc += ssim;
            cs_acc   += cs;
        }
    }

    // ---- block reduction: wave64 shuffle, then cross-wave via LDS
#pragma unroll
    for (int off = 32; off > 0; off >>= 1) {
        ssim_acc += __shfl_down(ssim_acc, off, 64);
        cs_acc   += __shfl_down(cs_acc,   off, 64);
    }
    int wave = tid >> 6, lane = tid & 63;
    if (lane == 0) { red[wave * 2] = ssim_acc; red[wave * 2 + 1] = cs_acc; }
    __syncthreads();
    if (tid == 0) {
        float s  = red[0] + red[2] + red[4] + red[6];
        float cc = red[1] + red[3] + red[5] + red[7];
        atomicAdd(&acc[nc * 2 + 0], s);
        atomicAdd(&acc[nc * 2 + 1], cc);
    }
}

// 2x2 average pool (all dims even at every scale -> no padding path needed)
__global__ __launch_bounds__(256) void downsample_kernel(
    const float* __restrict__ xi, const float* __restrict__ yi,
    float* __restrict__ xo, float* __restrict__ yo, int Hi, int Wi)
{
    int Ho = Hi >> 1, Wo = Wi >> 1;
    size_t total = (size_t)48 * Ho * Wo;
    size_t stride = (size_t)gridDim.x * blockDim.x;
    for (size_t i = (size_t)blockIdx.x * blockDim.x + threadIdx.x; i < total; i += stride) {
        int wo = (int)(i % Wo);
        size_t t = i / Wo;
        int ho = (int)(t % Ho);
        int nc = (int)(t / Ho);
        size_t ib = (size_t)nc * Hi * Wi + (size_t)(2 * ho) * Wi + 2 * wo;
        xo[i] = 0.25f * (xi[ib] + xi[ib + 1] + xi[ib + Wi] + xi[ib + Wi + 1]);
        yo[i] = 0.25f * (yi[ib] + yi[ib + 1] + yi[ib + Wi] + yi[ib + Wi + 1]);
    }
}

// Combine the 5 scales: prod_s val_s^{w_s}, mean over the 48 (n,c) pairs.
__global__ void finalize_kernel(const float* __restrict__ acc,
                                const float* __restrict__ weights,
                                float* __restrict__ out)
{
    int t = threadIdx.x;  // 64 threads
    float v = 0.f;
    if (t < 48) {
        float prod = 1.f;
#pragma unroll
        for (int s = 0; s < 5; ++s) {
            int O = (512 >> s) - HALO;
            float inv = 1.f / ((float)O * (float)O);
            float ssim = acc[s * 96 + t * 2 + 0] * inv;
            float cs   = acc[s * 96 + t * 2 + 1] * inv;
            float val = (s < 4) ? fmaxf(cs, 0.f) : ssim;  // mcs[:-1] + [ssim]
            prod *= powf(val, weights[s]);
        }
        v = prod;
    }
#pragma unroll
    for (int off = 32; off > 0; off >>= 1) v += __shfl_down(v, off, 64);
    if (t == 0) out[0] = v * (1.f / 48.f);
}

extern "C" void kernel_launch(void* const* d_in, const int* in_sizes, int n_in,
                              void* d_out, int out_size, void* d_ws, size_t ws_size,
                              hipStream_t stream) {
    const float* x = (const float*)d_in[0];       // (16,3,512,512)
    const float* y = (const float*)d_in[1];       // (16,3,512,512)
    // d_in[2] = window (3,1,11,11) -- recomputed on device (same formula)
    const float* weights = (const float*)d_in[3]; // (5,)
    float* out = (float*)d_out;
    float* ws = (float*)d_ws;

    // workspace layout (floats):
    //   [0,480)   : acc[5 scales][48 nc][2]   (ssim_sum, cs_sum)
    //   [512, ..) : downsampled pyramid x/y per scale
    float* acc = ws;
    float* xs1 = ws + 512;
    float* ys1 = xs1 + (size_t)48 * 256 * 256;
    float* xs2 = ys1 + (size_t)48 * 256 * 256;
    float* ys2 = xs2 + (size_t)48 * 128 * 128;
    float* xs3 = ys2 + (size_t)48 * 128 * 128;
    float* ys3 = xs3 + (size_t)48 * 64 * 64;
    float* xs4 = ys3 + (size_t)48 * 64 * 64;
    float* ys4 = xs4 + (size_t)48 * 32 * 32;
    // total ~8.36M floats = 33.4 MB

    hipMemsetAsync(acc, 0, 480 * sizeof(float), stream);  // ws is poisoned 0xAA

    dim3 blk(256);
    // scale 0 (512): OH=502 -> 16x16 tiles of 32
    ssim_scale_kernel<<<dim3(16, 16, 48), blk, 0, stream>>>(x, y, acc + 0 * 96, 512, 512);
    downsample_kernel<<<dim3(2048), blk, 0, stream>>>(x, y, xs1, ys1, 512, 512);
    // scale 1 (256): OH=246 -> 8x8
    ssim_scale_kernel<<<dim3(8, 8, 48), blk, 0, stream>>>(xs1, ys1, acc + 1 * 96, 256, 256);
    downsample_kernel<<<dim3(1024), blk, 0, stream>>>(xs1, ys1, xs2, ys2, 256, 256);
    // scale 2 (128): OH=118 -> 4x4
    ssim_scale_kernel<<<dim3(4, 4, 48), blk, 0, stream>>>(xs2, ys2, acc + 2 * 96, 128, 128);
    downsample_kernel<<<dim3(256), blk, 0, stream>>>(xs2, ys2, xs3, ys3, 128, 128);
    // scale 3 (64): OH=54 -> 2x2
    ssim_scale_kernel<<<dim3(2, 2, 48), blk, 0, stream>>>(xs3, ys3, acc + 3 * 96, 64, 64);
    downsample_kernel<<<dim3(64), blk, 0, stream>>>(xs3, ys3, xs4, ys4, 64, 64);
    // scale 4 (32): OH=22 -> 1x1
    ssim_scale_kernel<<<dim3(1, 1, 48), blk, 0, stream>>>(xs4, ys4, acc + 4 * 96, 32, 32);

    finalize_kernel<<<dim3(1), dim3(64), 0, stream>>>(acc, weights, out);
}

// Round 2
// 399.565 us; speedup vs baseline: 1.1166x; 1.1166x over previous
//
#include <hip/hip_runtime.h>

#define HALO 10
#define NT 256
#define SW 272   // LDS staging width (266 used)

__device__ __forceinline__ void make_gauss(float* g) {
    float s = 0.f;
#pragma unroll
    for (int i = 0; i < 11; ++i) {
        float d = (float)(i - 5);
        g[i] = expf(-d * d / 4.5f);   // sigma=1.5 -> 2*sigma^2 = 4.5
        s += g[i];
    }
    float inv = 1.f / s;
#pragma unroll
    for (int i = 0; i < 11; ++i) g[i] *= inv;
}

// Row-streaming separable SSIM. One thread per output column; vertical conv
// held in 55 in-flight register accumulators (11 rows x 5 fields), unroll-11
// so slot->weight mapping is static. LDS holds only 2 staged rows (x,y).
template <int ROWS>
__global__ __launch_bounds__(256) void ssim_stream_kernel(
    const float* __restrict__ x, const float* __restrict__ y,
    float* __restrict__ acc, int H, int W)
{
    const int OH = H - HALO, OW = W - HALO;
    const int nc = blockIdx.z;
    const int col0 = blockIdx.x * NT;
    const int r0 = blockIdx.y * ROWS;
    const int tid = threadIdx.x;
    const int c = col0 + tid;
    const bool colvalid = (c < OW);
    const int nrows_out = min(ROWS, OH - r0);
    const int nrows_in  = min(ROWS + HALO, H - r0);

    const float* xp = x + (size_t)nc * H * W;
    const float* yp = y + (size_t)nc * H * W;

    __shared__ float sA[2][SW];
    __shared__ float sB[2][SW];
    __shared__ float red[8];

    float g[11];
    make_gauss(g);

    // parity-adjusted 12-tap weights: even threads read [t..t+11], odd [t-1..t+10]
    float w2[12];
    const int par = tid & 1;
#pragma unroll
    for (int s = 0; s < 12; ++s) {
        float ge = (s < 11) ? g[s] : 0.f;
        float go = (s > 0) ? g[s - 1] : 0.f;
        w2[s] = par ? go : ge;
    }
    const int e = tid & ~1;   // aligned float2 base in the row buffer

    float accf[11][5];
#pragma unroll
    for (int k = 0; k < 11; ++k)
#pragma unroll
        for (int f = 0; f < 5; ++f) accf[k][f] = 0.f;

    float ssim_sum = 0.f, cs_sum = 0.f;

    // software-pipelined row loads (one row ahead)
    float vx0 = 0.f, vy0 = 0.f, vx1 = 0.f, vy1 = 0.f;
    {
        if (0 < nrows_in) {
            const size_t rowb = (size_t)r0 * W;
            if (c < W) { vx0 = xp[rowb + c]; vy0 = yp[rowb + c]; }
            if (tid < HALO && col0 + NT + tid < W) {
                vx1 = xp[rowb + col0 + NT + tid];
                vy1 = yp[rowb + col0 + NT + tid];
            }
        }
    }

    const int NI = ((nrows_out + HALO + 10) / 11) * 11;

    for (int ii = 0; ii < NI; ii += 11) {
#pragma unroll
        for (int u = 0; u < 11; ++u) {
            const int i = ii + u;
            const int p = i & 1;
            // stage row i from the pipelined registers
            sA[p][tid] = vx0; sB[p][tid] = vy0;
            if (tid < HALO) { sA[p][NT + tid] = vx1; sB[p][NT + tid] = vy1; }
            __syncthreads();
            // issue loads for row i+1 (consumed next iteration, after this
            // iteration's compute -- hides HBM latency)
            vx0 = 0.f; vy0 = 0.f; vx1 = 0.f; vy1 = 0.f;
            if (i + 1 < nrows_in) {
                const size_t rowb = (size_t)(r0 + i + 1) * W;
                if (c < W) { vx0 = xp[rowb + c]; vy0 = yp[rowb + c]; }
                if (tid < HALO && col0 + NT + tid < W) {
                    vx1 = xp[rowb + col0 + NT + tid];
                    vy1 = yp[rowb + col0 + NT + tid];
                }
            }
            // horizontal 11-tap conv via 6 aligned float2 LDS reads per field
            float a[12], b[12];
            const float2* pa = (const float2*)&sA[p][e];
            const float2* pb = (const float2*)&sB[p][e];
#pragma unroll
            for (int k2 = 0; k2 < 6; ++k2) {
                float2 qa = pa[k2], qb = pb[k2];
                a[2 * k2] = qa.x; a[2 * k2 + 1] = qa.y;
                b[2 * k2] = qb.x; b[2 * k2 + 1] = qb.y;
            }
            float hx = 0.f, hy = 0.f, hxx = 0.f, hyy = 0.f, hxy = 0.f;
#pragma unroll
            for (int s = 0; s < 12; ++s) {
                float av = a[s], bv = b[s], w = w2[s];
                hx  += w * av;
                hy  += w * bv;
                hxx += w * av * av;
                hyy += w * bv * bv;
                hxy += w * av * bv;
            }
            // vertical accumulate: slot k tracks output o == k (mod 11);
            // this row contributes weight g[(i - o) % 11] == g[(u-k) % 11]
#pragma unroll
            for (int k = 0; k < 11; ++k) {
                const float w = g[(u - k + 11) % 11];
                accf[k][0] += w * hx;
                accf[k][1] += w * hy;
                accf[k][2] += w * hxx;
                accf[k][3] += w * hyy;
                accf[k][4] += w * hxy;
            }
            // slot (u+1)%11 completed output o = i-10
            const int kc = (u + 1) % 11;
            const int o = i - HALO;
            if (o >= 0 && o < nrows_out && colvalid) {
                float mx = accf[kc][0], my = accf[kc][1];
                float mxx = accf[kc][2], myy = accf[kc][3], mxy = accf[kc][4];
                float mu_x2 = mx * mx, mu_y2 = my * my, mu_xy = mx * my;
                float sxq = mxx - mu_x2, syq = myy - mu_y2, sxyv = mxy - mu_xy;
                const float c1 = 1e-4f, c2 = 9e-4f;
                float cs = (2.f * sxyv + c2) / (sxq + syq + c2);
                float ssim = (2.f * mu_xy + c1) / (mu_x2 + mu_y2 + c1) * cs;
                ssim_sum += ssim;
                cs_sum += cs;
            }
#pragma unroll
            for (int f = 0; f < 5; ++f) accf[kc][f] = 0.f;
        }
    }

    // block reduction: wave64 shuffle, then cross-wave via LDS
#pragma unroll
    for (int off = 32; off > 0; off >>= 1) {
        ssim_sum += __shfl_down(ssim_sum, off, 64);
        cs_sum   += __shfl_down(cs_sum,   off, 64);
    }
    const int wave = tid >> 6, lane = tid & 63;
    if (lane == 0) { red[wave * 2] = ssim_sum; red[wave * 2 + 1] = cs_sum; }
    __syncthreads();
    if (tid == 0) {
        float s  = red[0] + red[2] + red[4] + red[6];
        float cc = red[1] + red[3] + red[5] + red[7];
        atomicAdd(&acc[nc * 2 + 0], s);
        atomicAdd(&acc[nc * 2 + 1], cc);
    }
}

// 2x2 average pool (all dims even at every scale -> no padding path needed)
__global__ __launch_bounds__(256) void downsample_kernel(
    const float* __restrict__ xi, const float* __restrict__ yi,
    float* __restrict__ xo, float* __restrict__ yo, int Hi, int Wi)
{
    int Ho = Hi >> 1, Wo = Wi >> 1;
    size_t total = (size_t)48 * Ho * Wo;
    size_t stride = (size_t)gridDim.x * blockDim.x;
    for (size_t i = (size_t)blockIdx.x * blockDim.x + threadIdx.x; i < total; i += stride) {
        int wo = (int)(i % Wo);
        size_t t = i / Wo;
        int ho = (int)(t % Ho);
        int nc = (int)(t / Ho);
        size_t ib = (size_t)nc * Hi * Wi + (size_t)(2 * ho) * Wi + 2 * wo;
        xo[i] = 0.25f * (xi[ib] + xi[ib + 1] + xi[ib + Wi] + xi[ib + Wi + 1]);
        yo[i] = 0.25f * (yi[ib] + yi[ib + 1] + yi[ib + Wi] + yi[ib + Wi + 1]);
    }
}

// Combine the 5 scales: prod_s val_s^{w_s}, mean over the 48 (n,c) pairs.
__global__ void finalize_kernel(const float* __restrict__ acc,
                                const float* __restrict__ weights,
                                float* __restrict__ out)
{
    int t = threadIdx.x;  // 64 threads
    float v = 0.f;
    if (t < 48) {
        float prod = 1.f;
#pragma unroll
        for (int s = 0; s < 5; ++s) {
            int O = (512 >> s) - HALO;
            float inv = 1.f / ((float)O * (float)O);
            float ssim = acc[s * 96 + t * 2 + 0] * inv;
            float cs   = acc[s * 96 + t * 2 + 1] * inv;
            float val = (s < 4) ? fmaxf(cs, 0.f) : ssim;  // mcs[:-1] + [ssim]
            prod *= powf(val, weights[s]);
        }
        v = prod;
    }
#pragma unroll
    for (int off = 32; off > 0; off >>= 1) v += __shfl_down(v, off, 64);
    if (t == 0) out[0] = v * (1.f / 48.f);
}

extern "C" void kernel_launch(void* const* d_in, const int* in_sizes, int n_in,
                              void* d_out, int out_size, void* d_ws, size_t ws_size,
                              hipStream_t stream) {
    const float* x = (const float*)d_in[0];       // (16,3,512,512)
    const float* y = (const float*)d_in[1];       // (16,3,512,512)
    const float* weights = (const float*)d_in[3]; // (5,)
    float* out = (float*)d_out;
    float* ws = (float*)d_ws;

    // workspace layout (floats):
    //   [0,480)   : acc[5 scales][48 nc][2]   (ssim_sum, cs_sum)
    //   [512, ..) : downsampled pyramid x/y per scale
    float* acc = ws;
    float* xs1 = ws + 512;
    float* ys1 = xs1 + (size_t)48 * 256 * 256;
    float* xs2 = ys1 + (size_t)48 * 256 * 256;
    float* ys2 = xs2 + (size_t)48 * 128 * 128;
    float* xs3 = ys2 + (size_t)48 * 128 * 128;
    float* ys3 = xs3 + (size_t)48 * 64 * 64;
    float* xs4 = ys3 + (size_t)48 * 64 * 64;
    float* ys4 = xs4 + (size_t)48 * 32 * 32;

    hipMemsetAsync(acc, 0, 480 * sizeof(float), stream);

    dim3 blk(256);
    // scale 0 (512x512): OW=502 -> 2 strips, OH=502 -> 8 chunks of 64
    ssim_stream_kernel<64><<<dim3(2, 8, 48), blk, 0, stream>>>(x, y, acc + 0 * 96, 512, 512);
    downsample_kernel<<<dim3(2048), blk, 0, stream>>>(x, y, xs1, ys1, 512, 512);
    // scale 1 (256): OW=246 -> 1 strip, OH=246 -> 8 chunks of 32
    ssim_stream_kernel<32><<<dim3(1, 8, 48), blk, 0, stream>>>(xs1, ys1, acc + 1 * 96, 256, 256);
    downsample_kernel<<<dim3(1024), blk, 0, stream>>>(xs1, ys1, xs2, ys2, 256, 256);
    // scale 2 (128): OH=118 -> 8 chunks of 16
    ssim_stream_kernel<16><<<dim3(1, 8, 48), blk, 0, stream>>>(xs2, ys2, acc + 2 * 96, 128, 128);
    downsample_kernel<<<dim3(256), blk, 0, stream>>>(xs2, ys2, xs3, ys3, 128, 128);
    // scale 3 (64): OH=54 -> 4 chunks of 16
    ssim_stream_kernel<16><<<dim3(1, 4, 48), blk, 0, stream>>>(xs3, ys3, acc + 3 * 96, 64, 64);
    downsample_kernel<<<dim3(64), blk, 0, stream>>>(xs3, ys3, xs4, ys4, 64, 64);
    // scale 4 (32): OH=22 -> 2 chunks of 16
    ssim_stream_kernel<16><<<dim3(1, 2, 48), blk, 0, stream>>>(xs4, ys4, acc + 4 * 96, 32, 32);

    finalize_kernel<<<dim3(1), dim3(64), 0, stream>>>(acc, weights, out);
}